// Round 11
// baseline (445.227 us; speedup 1.0000x reference)
//
#include <hip/hip_runtime.h>
#include <hip/hip_bf16.h>
#include <hip/hip_fp16.h>
#include <stdint.h>

// ---------------------------------------------------------------------------
// CCRGNN r24: budget shows 3 poles ~140 each (gnn, gemm1, gemm2). r23 proved
// gnn is NOT sync-bound (barrier'd == barrier-free == 140): it is LDS-pipe/
// latency bound (~1000 ds-ops/graph x ~11cy x 16 graphs/CU ~= wall). Diet:
//   - A (softmax weights) + HfT stored fp16: f16x8 halves ds-op count on the
//     dominant A round-trip. Weights pre-scaled 2^-8 (exact; cancels in
//     num/den since den sums the ROUNDED stored weights) -> fp16 safe to
//     e<=16.6, same bound class as r21's no-max-subtraction argument.
//   - slice 16.8->13.0 KB -> 5 blocks/CU = 10 graphs/CU (+25% concurrency).
// gemm2: proven 128^2 kernel, z=5 (1280 blocks = 5/CU = exact 32KB-LDS cap,
// +25% streams for its L3-latency-bound staging); P = 5 slices (42MB fits
// alias); gemm3 sums 5. gemm1/conv unchanged.
// ---------------------------------------------------------------------------

typedef float f32x4 __attribute__((ext_vector_type(4)));
typedef short bf16x8 __attribute__((ext_vector_type(8)));
typedef _Float16 f16x8 __attribute__((ext_vector_type(8)));

// monotone float<->uint encoding for atomicMax on floats
__device__ __forceinline__ unsigned fenc(float f) {
  int s = __float_as_int(f);
  return s < 0 ? ~(unsigned)s : ((unsigned)s | 0x80000000u);
}
__device__ __forceinline__ float fdec(unsigned u) {
  return (u & 0x80000000u) ? __int_as_float((int)(u & 0x7fffffffu))
                           : __int_as_float(~(int)u);
}

// wave-local LDS fence (gnn): drains this wave's LDS ops so other lanes'
// writes are visible. No s_barrier — waves never sync with each other.
__device__ __forceinline__ void wbar() {
  asm volatile("s_waitcnt lgkmcnt(0)" ::: "memory");
}

// ============ merged: wave-per-graph GNN + weight transpose ================
// bid < 2048 : gnn block = 2 independent graphs (g = bid*2 + wave)
// bid >= 2048: conv(tile = bid-2048)

__global__ __launch_bounds__(128) void gnn_conv_wpg(
    const float* __restrict__ x,
    const int* __restrict__ esrc, const int* __restrict__ edst,
    const float* __restrict__ W1, const float* __restrict__ a1s, const float* __restrict__ a1d, const float* __restrict__ b1,
    const float* __restrict__ W2, const float* __restrict__ a2s, const float* __restrict__ a2d, const float* __restrict__ b2,
    const float* __restrict__ W3, const float* __restrict__ a3s, const float* __restrict__ a3d, const float* __restrict__ b3,
    __hip_bfloat16* __restrict__ fA,         // tiled [4096,3328] KT=52
    const float* __restrict__ lW1, const float* __restrict__ lW2,
    short* __restrict__ W1T, short* __restrict__ W2T)
{
  __shared__ __align__(16) char smem[29024];
  const int tid = threadIdx.x;
  const int bid = blockIdx.x;

  if (bid >= 2048) {
    // ---- conv body (128 threads): fp32 [K0,N0] -> bf16 fragment-tiled ----
    float (*t)[260] = (float(*)[260])smem;
    const int cid = bid - 2048;
    const float* W; short* WT; int ktile, ntile, K0, N0, KT;
    if (cid < 4160) { W = lW1; WT = W1T; ktile = cid % 208; ntile = cid / 208; K0 = 3280; N0 = 5000; KT = 52; }
    else { int c2 = cid - 4160; W = lW2; WT = W2T; ktile = c2 % 320; ntile = c2 / 320; K0 = 5000; N0 = 1024; KT = 80; }

    const int kb = ktile * 16, nb = ntile * 256;
    const int wv = tid >> 6, lnc = tid & 63;
#pragma unroll
    for (int r = 0; r < 8; ++r) {
      int k = kb + wv * 8 + r;
      int n = nb + lnc * 4;
      f32x4 v = (f32x4){0.f, 0.f, 0.f, 0.f};
      if (k < K0 && n < N0) v = *(const f32x4*)&W[(size_t)k * N0 + n];   // N0 % 4 == 0
      *(f32x4*)&t[wv * 8 + r][lnc * 4] = v;
    }
    __syncthreads();
#pragma unroll
    for (int h = 0; h < 4; ++h) {
      int c = h * 128 + tid;
      int nl = c >> 1, kc = c & 1;
      int n = nb + nl, k = kb + kc * 8;
      union { bf16x8 v; __hip_bfloat16 b[8]; } z;
#pragma unroll
      for (int j = 0; j < 8; ++j) z.b[j] = __float2bfloat16(t[kc * 8 + j][nl]);
      int rt = n >> 7, mi = (n >> 4) & 7, lr = n & 15;
      int kt = k >> 6, kq = (k >> 5) & 1, lc = (k >> 3) & 3;
      size_t addr = ((((size_t)rt * KT) + kt) * 16 + mi * 2 + kq) * 512 + ((size_t)lr + 16 * lc) * 8;
      *(bf16x8*)&WT[addr] = z.v;
    }
    return;
  }

  // ---- gnn: wave-per-graph, barrier-free, fp16 A/HfT diet ----
  const int w = tid >> 6, ln = tid & 63;
  const int g = bid * 2 + w;

  // block-shared (read-only weights)
  float* sW3T  = (float*)(smem);                 // W3^T [9][68]
  float* a2buf = (float*)(smem + 2448);          // a2s | a2d
  float* a3sb  = (float*)(smem + 2960);
  float* a3db  = (float*)(smem + 3008);
  float* b3b   = (float*)(smem + 3056);
  // per-graph slice (one per wave), 12960 B
  char* sl = smem + 3104 + w * 12960;
  __half*   Ah   = (__half*)  (sl);              // [39][48] fp16 (scaled 2^-8)
  __half*   Hh2  = (__half*)  (sl + 3744);       // [39][72] half
  __half*   h1h  = (__half*)  (sl + 9360);       // [312] half
  __half*   HfT16= (__half*)  (sl + 9984);       // [9][48] fp16
  float*    xbuf = (float*)   (sl + 10848);      // 40 f
  float*    sarr = (float*)   (sl + 11008);      // 40 f
  float*    darr = (float*)   (sl + 11168);      // 40 f
  float*    den  = (float*)   (sl + 11328);      // 40 f (1/scaled-den)
  unsigned* umx  = (unsigned*)(sl + 11488);      // 132 u32
  unsigned* cntP = (unsigned*)(sl + 12016);      // 234 u32 (4-bit cnt[39][<=48])

  const int rt = g >> 7, mi = (g >> 4) & 7, lrow = g & 15;
  const size_t gbase = (size_t)rt * 52 * 8192 + (size_t)(mi * 2) * 512 + (size_t)lrow * 8;
#define COLADDR(c) (gbase + (size_t)((c) >> 6) * 8192 + (size_t)(((c) >> 5) & 1) * 512 \
                    + (size_t)(((c) >> 3) & 3) * 128 + ((c) & 7))

  // ---- setup ----
  for (int i = tid; i < 576; i += 128) { int k = i / 9, f3 = i - 9 * k; sW3T[f3 * 68 + k] = W3[i]; }
  a2buf[tid] = (tid < 64) ? a2s[tid] : a2d[tid - 64];
  if (tid < 9) { a3sb[tid] = a3s[tid]; a3db[tid] = a3d[tid]; b3b[tid] = b3[tid]; }
  for (int i = ln; i < 132; i += 64) umx[i] = 0u;
  for (int i = ln; i < 234; i += 64) cntP[i] = 0u;
  if (ln < 40) xbuf[ln] = 0.f;
  if (ln == 39) { sarr[39] = 0.f; darr[39] = 0.f; }
  __syncthreads();   // the ONLY block barrier (shared weights ready)

  float xv = 0.f;
  if (ln < 39) { xv = x[g * 39 + ln]; xbuf[ln] = xv; fA[COLADDR(ln)] = __float2bfloat16(xv); }
  float c_s = 0.f, c_d = 0.f;
  const float w1r = W1[ln & 7], b1r = b1[ln & 7];
#pragma unroll
  for (int ff = 0; ff < 8; ++ff) { float wv = W1[ff]; c_s += wv * a1s[ff]; c_d += wv * a1d[ff]; }
  const int eb = g * 312, nb0 = g * 39;
  if (ln < 39) atomicMax(&umx[0], fenc(xv));
#pragma unroll
  for (int it = 0; it < 6; ++it) {                     // cnt build (one pass)
    int e = it * 64 + ln;
    if (e < 351) {
      int ls, ld;
      if (e < 312) { ls = esrc[eb + e] - nb0; ld = edst[eb + e] - nb0; }
      else         { ls = e - 312; ld = ls; }
      atomicAdd(&cntP[ld * 6 + (ls >> 3)], 1u << (4 * (ls & 7)));
    }
  }
  wbar();

  // fused dense softmax -> Ah (fp16, scaled 2^-8) + 1/den (scaled).
  // Scale cancels exactly in num/den; den sums the ROUNDED stored weights.
  auto denseEW = [&](const float* sv, const float* dv) {
    if (ln < 39) {
      unsigned cw[6];
#pragma unroll
      for (int j = 0; j < 6; ++j) cw[j] = cntP[ln * 6 + j];
      float dval = dv[ln];
      __half* Ar = &Ah[ln * 48];
      float sum = 0.f;
#pragma unroll
      for (int c = 0; c < 5; ++c) {
        union { f16x8 v; __half h[8]; } z8;
#pragma unroll
        for (int j = 0; j < 8; ++j) {
          int s = c * 8 + j;
          float e = sv[s] + dval;
          e = (e > 0.f) ? e : 0.2f * e;
          unsigned cc = (cw[s >> 3] >> (4 * (s & 7))) & 0xFu;
          float ex = __expf(e) * 0.00390625f;        // 2^-8 fp16 headroom
          float wv = cc ? (float)cc * ex : 0.f;
          z8.h[j] = __float2half(wv);
          sum += (float)z8.h[j];                     // sum the rounded value
        }
        *(f16x8*)&Ar[c * 8] = z8.v;
      }
      den[ln] = 1.f / (sum + 3.9e-19f);              // 1e-16 * 2^-8
    }
  };

  // ========== layer 1 (Fin=1): softmax+q fused, no A storage ==========
  if (ln < 39) {
    unsigned cw[6];
#pragma unroll
    for (int j = 0; j < 6; ++j) cw[j] = cntP[ln * 6 + j];
    float dval = xbuf[ln] * c_d;
    float q = 0.f, dsum = 0.f;
#pragma unroll
    for (int c = 0; c < 10; ++c) {
      f32x4 x4 = *(const f32x4*)&xbuf[c * 4];
#pragma unroll
      for (int j = 0; j < 4; ++j) {
        int s = c * 4 + j;
        float xs = x4[j];
        float e = xs * c_s + dval;
        e = (e > 0.f) ? e : 0.2f * e;
        unsigned cc = (cw[s >> 3] >> (4 * (s & 7))) & 0xFu;
        float ex = __expf(e);
        float wv = cc ? (float)cc * ex : 0.f;
        q += wv * xs; dsum += wv;
      }
    }
    sarr[ln] = q * (1.f / (dsum + 1e-16f));
  }
  wbar();
#pragma unroll
  for (int it = 0; it < 5; ++it) {                     // h1 = relu(q W1 + b1)
    int slot = it * 64 + ln;                           // slot&7 == ln&7
    if (slot < 312) {
      int i = slot >> 3;
      float v = fmaxf(sarr[i] * w1r + b1r, 0.f);
      h1h[slot] = __float2half(v);
      fA[COLADDR(39 + slot)] = __float2bfloat16(v);
      atomicMax(&umx[1 + (ln & 7)], fenc(v));
    }
  }
  wbar();

  // ========== layer 2 (Fin=8, Fout=64) ==========
  float ht2r[40];                                      // Ht2 column f=ln
  {
    float w2k[8];
#pragma unroll
    for (int k = 0; k < 8; ++k) w2k[k] = W2[k * 64 + ln];
#pragma unroll
    for (int i = 0; i < 39; ++i) {
      f16x8 hr = *(const f16x8*)&h1h[i * 8];
      float hv = 0.f;
#pragma unroll
      for (int k = 0; k < 8; ++k) hv += (float)hr[k] * w2k[k];
      ht2r[i] = hv;
    }
    ht2r[39] = 0.f;
#pragma unroll
    for (int i = 0; i < 39; ++i) Hh2[i * 72 + ln] = __float2half(ht2r[i]);
  }
  wbar();
#pragma unroll
  for (int rr = 0; rr < 2; ++rr) {                     // s-dots then d-dots
    int t = rr * 64 + ln;
    if (t < 78) {
      int node = (t < 39) ? t : t - 39;
      const float* ab = a2buf + ((t < 39) ? 0 : 64);
      const __half* hr = &Hh2[node * 72];
      float s = 0.f;
#pragma unroll
      for (int c = 0; c < 8; ++c) {
        f16x8 hv = *(const f16x8*)&hr[c * 8];
        f32x4 a0 = *(const f32x4*)&ab[c * 8];
        f32x4 a1 = *(const f32x4*)&ab[c * 8 + 4];
        s += (float)hv[0] * a0.x + (float)hv[1] * a0.y + (float)hv[2] * a0.z + (float)hv[3] * a0.w
           + (float)hv[4] * a1.x + (float)hv[5] * a1.y + (float)hv[6] * a1.z + (float)hv[7] * a1.w;
      }
      if (t < 39) sarr[node] = s; else darr[node] = s;
    }
  }
  wbar();
  denseEW(sarr, darr);
  wbar();
  {                                                    // h2 = relu(Ah ht2r * invden + b2)
    const float b2r = b2[ln];
    for (int i = 0; i < 39; ++i) {
      float inv = den[i];
      const __half* Ar = &Ah[i * 48];
      float acc = 0.f;
#pragma unroll
      for (int c = 0; c < 5; ++c) {
        f16x8 a8 = *(const f16x8*)&Ar[c * 8];
#pragma unroll
        for (int j = 0; j < 8; ++j) acc += (float)a8[j] * ht2r[c * 8 + j];
      }
      float v = fmaxf(acc * inv + b2r, 0.f);
      Hh2[i * 72 + ln] = __float2half(v);
      fA[COLADDR(351 + i * 64 + ln)] = __float2bfloat16(v);
      atomicMax(&umx[9 + ln], fenc(v));
    }
  }
  wbar();

  // ========== layer 3 (Fin=64, Fout=9) ==========
#pragma unroll
  for (int it = 0; it < 6; ++it) {                     // Ht3^T = (h2 @ W3)^T, fp16
    int slot = it * 64 + ln;
    if (slot < 351) {
      int i = slot / 9, f3 = slot - 9 * i;
      const __half* hr = &Hh2[i * 72];
      const float* wr = &sW3T[f3 * 68];
      float acc = 0.f;
#pragma unroll
      for (int c = 0; c < 8; ++c) {
        f16x8 hv = *(const f16x8*)&hr[c * 8];
        f32x4 w0 = *(const f32x4*)&wr[c * 8];
        f32x4 w1 = *(const f32x4*)&wr[c * 8 + 4];
        acc += (float)hv[0] * w0.x + (float)hv[1] * w0.y + (float)hv[2] * w0.z + (float)hv[3] * w0.w
             + (float)hv[4] * w1.x + (float)hv[5] * w1.y + (float)hv[6] * w1.z + (float)hv[7] * w1.w;
      }
      HfT16[f3 * 48 + i] = __float2half(acc);
    }
  }
  if (ln < 9) HfT16[ln * 48 + 39] = __float2half(0.f);
  wbar();
#pragma unroll
  for (int rr = 0; rr < 2; ++rr) {
    int t = rr * 64 + ln;
    if (t < 78) {
      int node = (t < 39) ? t : t - 39;
      const float* av = (t < 39) ? a3sb : a3db;
      float s = 0.f;
#pragma unroll
      for (int f3 = 0; f3 < 9; ++f3) s += (float)HfT16[f3 * 48 + node] * av[f3];
      if (t < 39) sarr[node] = s; else darr[node] = s;
    }
  }
  wbar();
  denseEW(sarr, darr);
  wbar();
#pragma unroll
  for (int it = 0; it < 6; ++it) {                     // h3 = relu(Ah Ht3 * invden + b3)
    int slot = it * 64 + ln;
    if (slot < 351) {
      int i = slot / 9, f3 = slot - 9 * i;
      float inv = den[i];
      const __half* Ar = &Ah[i * 48];
      const __half* Hr = &HfT16[f3 * 48];
      float acc = 0.f;
#pragma unroll
      for (int c = 0; c < 5; ++c) {
        f16x8 a8 = *(const f16x8*)&Ar[c * 8];
        f16x8 h8 = *(const f16x8*)&Hr[c * 8];
#pragma unroll
        for (int j = 0; j < 8; ++j) acc += (float)a8[j] * (float)h8[j];
      }
      float v = fmaxf(acc * inv + b3b[f3], 0.f);
      fA[COLADDR(2847 + slot)] = __float2bfloat16(v);
      atomicMax(&umx[73 + f3], fenc(v));
    }
  }
  wbar();

  // ---- segment maxes + pad (cols 3198..3327) ----
#pragma unroll
  for (int it = 0; it < 3; ++it) {
    int idx = it * 64 + ln;
    if (idx < 130) {
      int c = 3198 + idx;
      float v = (idx < 82) ? fdec(umx[idx]) : 0.f;
      fA[COLADDR(c)] = __float2bfloat16(v);
    }
  }
#undef COLADDR
}

// ======================= tiled bf16 MFMA GEMM ==============================

__device__ __forceinline__ void gld_lds16(const void* gptr, void* l) {
  typedef const __attribute__((address_space(1))) unsigned int GU;
  typedef __attribute__((address_space(3))) unsigned int LU;
  __builtin_amdgcn_global_load_lds((GU*)gptr, (LU*)l, 16, 0, 0);
}

// gemm1: C tiled bf16 (next GEMM's A, outKT = Nn/64), +bias +relu; 128^2.
__global__ __launch_bounds__(256) void gemm_tiled(
    const short* __restrict__ A, const short* __restrict__ B,
    const float* __restrict__ bias, int Nreal,
    void* __restrict__ Cout, int Nn, int KT, int ktPerSplit, int outKT)
{
  __shared__ __align__(16) short lA[8192];
  __shared__ __align__(16) short lB[8192];
  const int tid = threadIdx.x;
  const int w = tid >> 6, L = tid & 63;
  const int lrow = L & 15, lch = L >> 4;
  const int mt = blockIdx.y, nt = blockIdx.x;
  const int mw = (w >> 1) * 4, nw = (w & 1) * 4;
  const int kt0 = blockIdx.z * ktPerSplit, kt1 = kt0 + ktPerSplit;

  const short* Ab = A + ((size_t)mt * KT) * 8192 + (size_t)L * 8;
  const short* Bb = B + ((size_t)nt * KT) * 8192 + (size_t)L * 8;

  f32x4 acc[4][4] = {};

  for (int kt = kt0; kt < kt1; ++kt) {
    const short* Ak = Ab + (size_t)kt * 8192;
    const short* Bk = Bb + (size_t)kt * 8192;
#pragma unroll
    for (int j = 0; j < 4; ++j) {
      int st = w * 4 + j;
      gld_lds16(Ak + st * 512, &lA[st * 512]);
      gld_lds16(Bk + st * 512, &lB[st * 512]);
    }
    __syncthreads();
#pragma unroll
    for (int kk = 0; kk < 2; ++kk) {
      bf16x8 af[4], bfr[4];
#pragma unroll
      for (int i = 0; i < 4; ++i) {
        af[i]  = *(const bf16x8*)&lA[((mw + i) * 2 + kk) * 512 + L * 8];
        bfr[i] = *(const bf16x8*)&lB[((nw + i) * 2 + kk) * 512 + L * 8];
      }
#pragma unroll
      for (int i = 0; i < 4; ++i)
#pragma unroll
        for (int j = 0; j < 4; ++j)
          acc[i][j] = __builtin_amdgcn_mfma_f32_16x16x32_bf16(af[i], bfr[j], acc[i][j], 0, 0, 0);
    }
    __syncthreads();
  }

  __hip_bfloat16* C = (__hip_bfloat16*)Cout;
#pragma unroll
  for (int j = 0; j < 4; ++j) {
    int n = nt * 128 + (nw + j) * 16 + lrow;
    float bn = (n < Nreal) ? bias[n] : 0.f;
    int kt = n >> 6, kq = (n >> 5) & 1, lc2 = (n >> 3) & 3, j2 = n & 7;
#pragma unroll
    for (int i = 0; i < 4; ++i) {
      int mi = mw + i;
      size_t base = ((((size_t)mt * outKT + kt) * 16) + mi * 2 + kq) * 512
                    + (size_t)(lch * 4) * 8 + (size_t)lc2 * 128 + j2;
#pragma unroll
      for (int r = 0; r < 4; ++r)
        C[base + r * 8] = __float2bfloat16(fmaxf(acc[i][j][r] + bn, 0.f));
    }
  }
}

// gemm2: 128^2, split-K z=5 (ktPerSplit=16) -> 1280 blocks = 5/CU (exact
// 32KB-LDS cap). fp16 partials P[5][4096][1024].
__global__ __launch_bounds__(256) void gemm2_128(
    const short* __restrict__ A, const short* __restrict__ B,
    __half* __restrict__ P)
{
  __shared__ __align__(16) short lA[8192];
  __shared__ __align__(16) short lB[8192];
  const int tid = threadIdx.x;
  const int w = tid >> 6, L = tid & 63;
  const int lrow = L & 15, lch = L >> 4;
  const int mt = blockIdx.y, nt = blockIdx.x, zz = blockIdx.z;
  const int mw = (w >> 1) * 4, nw = (w & 1) * 4;
  const int kt0 = zz * 16, kt1 = kt0 + 16;   // K=5120, KT=80, z=5

  const short* Ab = A + ((size_t)mt * 80) * 8192 + (size_t)L * 8;
  const short* Bb = B + ((size_t)nt * 80) * 8192 + (size_t)L * 8;

  f32x4 acc[4][4] = {};

  for (int kt = kt0; kt < kt1; ++kt) {
    const short* Ak = Ab + (size_t)kt * 8192;
    const short* Bk = Bb + (size_t)kt * 8192;
#pragma unroll
    for (int j = 0; j < 4; ++j) {
      int st = w * 4 + j;
      gld_lds16(Ak + st * 512, &lA[st * 512]);
      gld_lds16(Bk + st * 512, &lB[st * 512]);
    }
    __syncthreads();
#pragma unroll
    for (int kk = 0; kk < 2; ++kk) {
      bf16x8 af[4], bfr[4];
#pragma unroll
      for (int i = 0; i < 4; ++i) {
        af[i]  = *(const bf16x8*)&lA[((mw + i) * 2 + kk) * 512 + L * 8];
        bfr[i] = *(const bf16x8*)&lB[((nw + i) * 2 + kk) * 512 + L * 8];
      }
#pragma unroll
      for (int i = 0; i < 4; ++i)
#pragma unroll
        for (int j = 0; j < 4; ++j)
          acc[i][j] = __builtin_amdgcn_mfma_f32_16x16x32_bf16(af[i], bfr[j], acc[i][j], 0, 0, 0);
    }
    __syncthreads();
  }

  __half* Pz = P + (size_t)zz * 4096 * 1024;
#pragma unroll
  for (int j = 0; j < 4; ++j) {
    int n = nt * 128 + (nw + j) * 16 + lrow;
#pragma unroll
    for (int i = 0; i < 4; ++i)
#pragma unroll
      for (int r = 0; r < 4; ++r) {
        int m = mt * 128 + (mw + i) * 16 + lch * 4 + r;
        Pz[(size_t)m * 1024 + n] = __float2half(acc[i][j][r]);
      }
  }
}

// == final: relu(P0..P4+b2) @ W3 + b3 -> fp32 out (reduce fused) ============

__global__ __launch_bounds__(256) void gemm3_fused(
    const __half* __restrict__ P,     // [5][4096][1024] fp16
    const float* __restrict__ b2v,    // lb2 [1024]
    const float* __restrict__ W3,     // lW3 [1024,9]
    const float* __restrict__ b3v,    // lb3 [9]
    float* __restrict__ out)          // [4096,9]
{
  __shared__ float sW3[9 * 1024];
  int tid = threadIdx.x;
  for (int i = tid; i < 9216; i += 256) { int k = i / 9, j = i - 9 * k; sW3[j * 1024 + k] = W3[i]; }
  __syncthreads();
  int row = blockIdx.x * 4 + (tid >> 6);
  int lane = tid & 63;
  const __half* p0 = P + (size_t)row * 1024;
  const size_t S = (size_t)4096 * 1024;
  float acc[9] = {0, 0, 0, 0, 0, 0, 0, 0, 0};
  for (int t = 0; t < 16; ++t) {
    int k = lane + 64 * t;
    float c = b2v[k];
#pragma unroll
    for (int z = 0; z < 5; ++z) c += __half2float(p0[k + (size_t)z * S]);
    c = fmaxf(c, 0.f);
#pragma unroll
    for (int j = 0; j < 9; ++j) acc[j] += c * sW3[j * 1024 + k];
  }
#pragma unroll
  for (int j = 0; j < 9; ++j) {
    float v = acc[j];
    v += __shfl_down(v, 32, 64);
    v += __shfl_down(v, 16, 64);
    v += __shfl_down(v, 8, 64);
    v += __shfl_down(v, 4, 64);
    v += __shfl_down(v, 2, 64);
    v += __shfl_down(v, 1, 64);
    if (lane == 0) out[(size_t)row * 9 + j] = v + b3v[j];
  }
}

// ============================= launch =======================================

extern "C" void kernel_launch(void* const* d_in, const int* in_sizes, int n_in,
                              void* d_out, int out_size, void* d_ws, size_t ws_size,
                              hipStream_t stream)
{
  const float* x   = (const float*)d_in[0];
  const int*   ei  = (const int*)d_in[1];
  const float* W1  = (const float*)d_in[3];
  const float* a1s = (const float*)d_in[4];
  const float* a1d = (const float*)d_in[5];
  const float* b1  = (const float*)d_in[6];
  const float* W2  = (const float*)d_in[7];
  const float* a2s = (const float*)d_in[8];
  const float* a2d = (const float*)d_in[9];
  const float* b2  = (const float*)d_in[10];
  const float* W3  = (const float*)d_in[11];
  const float* a3s = (const float*)d_in[12];
  const float* a3d = (const float*)d_in[13];
  const float* b3  = (const float*)d_in[14];
  const float* lW1 = (const float*)d_in[15];
  const float* lb1 = (const float*)d_in[16];
  const float* lW2 = (const float*)d_in[17];
  const float* lb2 = (const float*)d_in[18];
  const float* lW3 = (const float*)d_in[19];
  const float* lb3 = (const float*)d_in[20];

  const int E = 4096 * 39 * 8;
  const int* esrc = ei;
  const int* edst = ei + E;

  // ws (bf16 elems): fA 13.6M | W1T 17.0M | C1 21.0M | W2T 5.2M  (~114 MB)
  short* fA  = (short*)d_ws;                       // tiled [4096,3328] KT=52
  short* W1T = fA  + (size_t)4096 * 3328;          // tiled [5120,3328] KT=52
  short* C1  = W1T + (size_t)5120 * 3328;          // tiled [4096,5120] KT=80
  short* W2T = C1  + (size_t)4096 * 5120;          // tiled [1024,5120] KT=80
  __half* P  = (__half*)d_ws;                      // 5x[4096,1024] fp16 (41.9MB), aliases fA+W1T (dead)

  gnn_conv_wpg<<<7488, 128, 0, stream>>>(x, esrc, edst,
                                         W1, a1s, a1d, b1, W2, a2s, a2d, b2, W3, a3s, a3d, b3,
                                         (__hip_bfloat16*)fA, lW1, lW2, W1T, W2T);
  gemm_tiled<<<dim3(40, 32, 1), 256, 0, stream>>>(fA, W1T, lb1, 5000, C1, 5120, 52, 52, 80);
  gemm2_128<<<dim3(8, 32, 5), 256, 0, stream>>>(C1, W2T, P);
  gemm3_fused<<<1024, 256, 0, stream>>>(P, lb2, lW3, lb3, (float*)d_out);
}

// Round 12
// 427.521 us; speedup vs baseline: 1.0414x; 1.0414x over previous
//
#include <hip/hip_runtime.h>
#include <hip/hip_bf16.h>
#include <hip/hip_fp16.h>
#include <stdint.h>

// ---------------------------------------------------------------------------
// CCRGNN r25: gemm2 XCD-pinned-B schedule. Diagnosis: gemm2's 1024 resident
// blocks (4/CU) have CONCURRENT working set A42+B10.5=52MB >> 32MB L2 ->
// both operands stream from L3 at ~4.8TB/s (670MB/140us); temporal swizzles
// (r17/r19) and tile shapes (r22 256^2, r24 z=5) can't fix a concurrency
// problem. Fix: nt = bid&7 -> XCD x (hw round-robin bid%8) serves ONLY
// nt=x, so its 1.3MB B-panel stays hot in its private L2 for all 128 of
// its resident blocks (kills B's 335MB of L3 traffic); A streams once per
// XCD. Grid flattened (1024): nt=bid&7, mt=(bid>>3)&31, z=bid>>8. z=4,
// P=4 fp16 slices. gnn (r24 fp16-diet wpg) / gemm1 / conv unchanged.
// ---------------------------------------------------------------------------

typedef float f32x4 __attribute__((ext_vector_type(4)));
typedef short bf16x8 __attribute__((ext_vector_type(8)));
typedef _Float16 f16x8 __attribute__((ext_vector_type(8)));

// monotone float<->uint encoding for atomicMax on floats
__device__ __forceinline__ unsigned fenc(float f) {
  int s = __float_as_int(f);
  return s < 0 ? ~(unsigned)s : ((unsigned)s | 0x80000000u);
}
__device__ __forceinline__ float fdec(unsigned u) {
  return (u & 0x80000000u) ? __int_as_float((int)(u & 0x7fffffffu))
                           : __int_as_float(~(int)u);
}

// wave-local LDS fence (gnn): drains this wave's LDS ops so other lanes'
// writes are visible. No s_barrier — waves never sync with each other.
__device__ __forceinline__ void wbar() {
  asm volatile("s_waitcnt lgkmcnt(0)" ::: "memory");
}

// ============ merged: wave-per-graph GNN + weight transpose ================
// bid < 2048 : gnn block = 2 independent graphs (g = bid*2 + wave)
// bid >= 2048: conv(tile = bid-2048)

__global__ __launch_bounds__(128) void gnn_conv_wpg(
    const float* __restrict__ x,
    const int* __restrict__ esrc, const int* __restrict__ edst,
    const float* __restrict__ W1, const float* __restrict__ a1s, const float* __restrict__ a1d, const float* __restrict__ b1,
    const float* __restrict__ W2, const float* __restrict__ a2s, const float* __restrict__ a2d, const float* __restrict__ b2,
    const float* __restrict__ W3, const float* __restrict__ a3s, const float* __restrict__ a3d, const float* __restrict__ b3,
    __hip_bfloat16* __restrict__ fA,         // tiled [4096,3328] KT=52
    const float* __restrict__ lW1, const float* __restrict__ lW2,
    short* __restrict__ W1T, short* __restrict__ W2T)
{
  __shared__ __align__(16) char smem[29024];
  const int tid = threadIdx.x;
  const int bid = blockIdx.x;

  if (bid >= 2048) {
    // ---- conv body (128 threads): fp32 [K0,N0] -> bf16 fragment-tiled ----
    float (*t)[260] = (float(*)[260])smem;
    const int cid = bid - 2048;
    const float* W; short* WT; int ktile, ntile, K0, N0, KT;
    if (cid < 4160) { W = lW1; WT = W1T; ktile = cid % 208; ntile = cid / 208; K0 = 3280; N0 = 5000; KT = 52; }
    else { int c2 = cid - 4160; W = lW2; WT = W2T; ktile = c2 % 320; ntile = c2 / 320; K0 = 5000; N0 = 1024; KT = 80; }

    const int kb = ktile * 16, nb = ntile * 256;
    const int wv = tid >> 6, lnc = tid & 63;
#pragma unroll
    for (int r = 0; r < 8; ++r) {
      int k = kb + wv * 8 + r;
      int n = nb + lnc * 4;
      f32x4 v = (f32x4){0.f, 0.f, 0.f, 0.f};
      if (k < K0 && n < N0) v = *(const f32x4*)&W[(size_t)k * N0 + n];   // N0 % 4 == 0
      *(f32x4*)&t[wv * 8 + r][lnc * 4] = v;
    }
    __syncthreads();
#pragma unroll
    for (int h = 0; h < 4; ++h) {
      int c = h * 128 + tid;
      int nl = c >> 1, kc = c & 1;
      int n = nb + nl, k = kb + kc * 8;
      union { bf16x8 v; __hip_bfloat16 b[8]; } z;
#pragma unroll
      for (int j = 0; j < 8; ++j) z.b[j] = __float2bfloat16(t[kc * 8 + j][nl]);
      int rt = n >> 7, mi = (n >> 4) & 7, lr = n & 15;
      int kt = k >> 6, kq = (k >> 5) & 1, lc = (k >> 3) & 3;
      size_t addr = ((((size_t)rt * KT) + kt) * 16 + mi * 2 + kq) * 512 + ((size_t)lr + 16 * lc) * 8;
      *(bf16x8*)&WT[addr] = z.v;
    }
    return;
  }

  // ---- gnn: wave-per-graph, barrier-free, fp16 A/HfT diet ----
  const int w = tid >> 6, ln = tid & 63;
  const int g = bid * 2 + w;

  // block-shared (read-only weights)
  float* sW3T  = (float*)(smem);                 // W3^T [9][68]
  float* a2buf = (float*)(smem + 2448);          // a2s | a2d
  float* a3sb  = (float*)(smem + 2960);
  float* a3db  = (float*)(smem + 3008);
  float* b3b   = (float*)(smem + 3056);
  // per-graph slice (one per wave), 12960 B
  char* sl = smem + 3104 + w * 12960;
  __half*   Ah   = (__half*)  (sl);              // [39][48] fp16 (scaled 2^-8)
  __half*   Hh2  = (__half*)  (sl + 3744);       // [39][72] half
  __half*   h1h  = (__half*)  (sl + 9360);       // [312] half
  __half*   HfT16= (__half*)  (sl + 9984);       // [9][48] fp16
  float*    xbuf = (float*)   (sl + 10848);      // 40 f
  float*    sarr = (float*)   (sl + 11008);      // 40 f
  float*    darr = (float*)   (sl + 11168);      // 40 f
  float*    den  = (float*)   (sl + 11328);      // 40 f (1/scaled-den)
  unsigned* umx  = (unsigned*)(sl + 11488);      // 132 u32
  unsigned* cntP = (unsigned*)(sl + 12016);      // 234 u32 (4-bit cnt[39][<=48])

  const int rt = g >> 7, mi = (g >> 4) & 7, lrow = g & 15;
  const size_t gbase = (size_t)rt * 52 * 8192 + (size_t)(mi * 2) * 512 + (size_t)lrow * 8;
#define COLADDR(c) (gbase + (size_t)((c) >> 6) * 8192 + (size_t)(((c) >> 5) & 1) * 512 \
                    + (size_t)(((c) >> 3) & 3) * 128 + ((c) & 7))

  // ---- setup ----
  for (int i = tid; i < 576; i += 128) { int k = i / 9, f3 = i - 9 * k; sW3T[f3 * 68 + k] = W3[i]; }
  a2buf[tid] = (tid < 64) ? a2s[tid] : a2d[tid - 64];
  if (tid < 9) { a3sb[tid] = a3s[tid]; a3db[tid] = a3d[tid]; b3b[tid] = b3[tid]; }
  for (int i = ln; i < 132; i += 64) umx[i] = 0u;
  for (int i = ln; i < 234; i += 64) cntP[i] = 0u;
  if (ln < 40) xbuf[ln] = 0.f;
  if (ln == 39) { sarr[39] = 0.f; darr[39] = 0.f; }
  __syncthreads();   // the ONLY block barrier (shared weights ready)

  float xv = 0.f;
  if (ln < 39) { xv = x[g * 39 + ln]; xbuf[ln] = xv; fA[COLADDR(ln)] = __float2bfloat16(xv); }
  float c_s = 0.f, c_d = 0.f;
  const float w1r = W1[ln & 7], b1r = b1[ln & 7];
#pragma unroll
  for (int ff = 0; ff < 8; ++ff) { float wv = W1[ff]; c_s += wv * a1s[ff]; c_d += wv * a1d[ff]; }
  const int eb = g * 312, nb0 = g * 39;
  if (ln < 39) atomicMax(&umx[0], fenc(xv));
#pragma unroll
  for (int it = 0; it < 6; ++it) {                     // cnt build (one pass)
    int e = it * 64 + ln;
    if (e < 351) {
      int ls, ld;
      if (e < 312) { ls = esrc[eb + e] - nb0; ld = edst[eb + e] - nb0; }
      else         { ls = e - 312; ld = ls; }
      atomicAdd(&cntP[ld * 6 + (ls >> 3)], 1u << (4 * (ls & 7)));
    }
  }
  wbar();

  // fused dense softmax -> Ah (fp16, scaled 2^-8) + 1/den (scaled).
  // Scale cancels exactly in num/den; den sums the ROUNDED stored weights.
  auto denseEW = [&](const float* sv, const float* dv) {
    if (ln < 39) {
      unsigned cw[6];
#pragma unroll
      for (int j = 0; j < 6; ++j) cw[j] = cntP[ln * 6 + j];
      float dval = dv[ln];
      __half* Ar = &Ah[ln * 48];
      float sum = 0.f;
#pragma unroll
      for (int c = 0; c < 5; ++c) {
        union { f16x8 v; __half h[8]; } z8;
#pragma unroll
        for (int j = 0; j < 8; ++j) {
          int s = c * 8 + j;
          float e = sv[s] + dval;
          e = (e > 0.f) ? e : 0.2f * e;
          unsigned cc = (cw[s >> 3] >> (4 * (s & 7))) & 0xFu;
          float ex = __expf(e) * 0.00390625f;        // 2^-8 fp16 headroom
          float wv = cc ? (float)cc * ex : 0.f;
          z8.h[j] = __float2half(wv);
          sum += (float)z8.h[j];                     // sum the rounded value
        }
        *(f16x8*)&Ar[c * 8] = z8.v;
      }
      den[ln] = 1.f / (sum + 3.9e-19f);              // 1e-16 * 2^-8
    }
  };

  // ========== layer 1 (Fin=1): softmax+q fused, no A storage ==========
  if (ln < 39) {
    unsigned cw[6];
#pragma unroll
    for (int j = 0; j < 6; ++j) cw[j] = cntP[ln * 6 + j];
    float dval = xbuf[ln] * c_d;
    float q = 0.f, dsum = 0.f;
#pragma unroll
    for (int c = 0; c < 10; ++c) {
      f32x4 x4 = *(const f32x4*)&xbuf[c * 4];
#pragma unroll
      for (int j = 0; j < 4; ++j) {
        int s = c * 4 + j;
        float xs = x4[j];
        float e = xs * c_s + dval;
        e = (e > 0.f) ? e : 0.2f * e;
        unsigned cc = (cw[s >> 3] >> (4 * (s & 7))) & 0xFu;
        float ex = __expf(e);
        float wv = cc ? (float)cc * ex : 0.f;
        q += wv * xs; dsum += wv;
      }
    }
    sarr[ln] = q * (1.f / (dsum + 1e-16f));
  }
  wbar();
#pragma unroll
  for (int it = 0; it < 5; ++it) {                     // h1 = relu(q W1 + b1)
    int slot = it * 64 + ln;                           // slot&7 == ln&7
    if (slot < 312) {
      int i = slot >> 3;
      float v = fmaxf(sarr[i] * w1r + b1r, 0.f);
      h1h[slot] = __float2half(v);
      fA[COLADDR(39 + slot)] = __float2bfloat16(v);
      atomicMax(&umx[1 + (ln & 7)], fenc(v));
    }
  }
  wbar();

  // ========== layer 2 (Fin=8, Fout=64) ==========
  float ht2r[40];                                      // Ht2 column f=ln
  {
    float w2k[8];
#pragma unroll
    for (int k = 0; k < 8; ++k) w2k[k] = W2[k * 64 + ln];
#pragma unroll
    for (int i = 0; i < 39; ++i) {
      f16x8 hr = *(const f16x8*)&h1h[i * 8];
      float hv = 0.f;
#pragma unroll
      for (int k = 0; k < 8; ++k) hv += (float)hr[k] * w2k[k];
      ht2r[i] = hv;
    }
    ht2r[39] = 0.f;
#pragma unroll
    for (int i = 0; i < 39; ++i) Hh2[i * 72 + ln] = __float2half(ht2r[i]);
  }
  wbar();
#pragma unroll
  for (int rr = 0; rr < 2; ++rr) {                     // s-dots then d-dots
    int t = rr * 64 + ln;
    if (t < 78) {
      int node = (t < 39) ? t : t - 39;
      const float* ab = a2buf + ((t < 39) ? 0 : 64);
      const __half* hr = &Hh2[node * 72];
      float s = 0.f;
#pragma unroll
      for (int c = 0; c < 8; ++c) {
        f16x8 hv = *(const f16x8*)&hr[c * 8];
        f32x4 a0 = *(const f32x4*)&ab[c * 8];
        f32x4 a1 = *(const f32x4*)&ab[c * 8 + 4];
        s += (float)hv[0] * a0.x + (float)hv[1] * a0.y + (float)hv[2] * a0.z + (float)hv[3] * a0.w
           + (float)hv[4] * a1.x + (float)hv[5] * a1.y + (float)hv[6] * a1.z + (float)hv[7] * a1.w;
      }
      if (t < 39) sarr[node] = s; else darr[node] = s;
    }
  }
  wbar();
  denseEW(sarr, darr);
  wbar();
  {                                                    // h2 = relu(Ah ht2r * invden + b2)
    const float b2r = b2[ln];
    for (int i = 0; i < 39; ++i) {
      float inv = den[i];
      const __half* Ar = &Ah[i * 48];
      float acc = 0.f;
#pragma unroll
      for (int c = 0; c < 5; ++c) {
        f16x8 a8 = *(const f16x8*)&Ar[c * 8];
#pragma unroll
        for (int j = 0; j < 8; ++j) acc += (float)a8[j] * ht2r[c * 8 + j];
      }
      float v = fmaxf(acc * inv + b2r, 0.f);
      Hh2[i * 72 + ln] = __float2half(v);
      fA[COLADDR(351 + i * 64 + ln)] = __float2bfloat16(v);
      atomicMax(&umx[9 + ln], fenc(v));
    }
  }
  wbar();

  // ========== layer 3 (Fin=64, Fout=9) ==========
#pragma unroll
  for (int it = 0; it < 6; ++it) {                     // Ht3^T = (h2 @ W3)^T, fp16
    int slot = it * 64 + ln;
    if (slot < 351) {
      int i = slot / 9, f3 = slot - 9 * i;
      const __half* hr = &Hh2[i * 72];
      const float* wr = &sW3T[f3 * 68];
      float acc = 0.f;
#pragma unroll
      for (int c = 0; c < 8; ++c) {
        f16x8 hv = *(const f16x8*)&hr[c * 8];
        f32x4 w0 = *(const f32x4*)&wr[c * 8];
        f32x4 w1 = *(const f32x4*)&wr[c * 8 + 4];
        acc += (float)hv[0] * w0.x + (float)hv[1] * w0.y + (float)hv[2] * w0.z + (float)hv[3] * w0.w
             + (float)hv[4] * w1.x + (float)hv[5] * w1.y + (float)hv[6] * w1.z + (float)hv[7] * w1.w;
      }
      HfT16[f3 * 48 + i] = __float2half(acc);
    }
  }
  if (ln < 9) HfT16[ln * 48 + 39] = __float2half(0.f);
  wbar();
#pragma unroll
  for (int rr = 0; rr < 2; ++rr) {
    int t = rr * 64 + ln;
    if (t < 78) {
      int node = (t < 39) ? t : t - 39;
      const float* av = (t < 39) ? a3sb : a3db;
      float s = 0.f;
#pragma unroll
      for (int f3 = 0; f3 < 9; ++f3) s += (float)HfT16[f3 * 48 + node] * av[f3];
      if (t < 39) sarr[node] = s; else darr[node] = s;
    }
  }
  wbar();
  denseEW(sarr, darr);
  wbar();
#pragma unroll
  for (int it = 0; it < 6; ++it) {                     // h3 = relu(Ah Ht3 * invden + b3)
    int slot = it * 64 + ln;
    if (slot < 351) {
      int i = slot / 9, f3 = slot - 9 * i;
      float inv = den[i];
      const __half* Ar = &Ah[i * 48];
      const __half* Hr = &HfT16[f3 * 48];
      float acc = 0.f;
#pragma unroll
      for (int c = 0; c < 5; ++c) {
        f16x8 a8 = *(const f16x8*)&Ar[c * 8];
        f16x8 h8 = *(const f16x8*)&Hr[c * 8];
#pragma unroll
        for (int j = 0; j < 8; ++j) acc += (float)a8[j] * (float)h8[j];
      }
      float v = fmaxf(acc * inv + b3b[f3], 0.f);
      fA[COLADDR(2847 + slot)] = __float2bfloat16(v);
      atomicMax(&umx[73 + f3], fenc(v));
    }
  }
  wbar();

  // ---- segment maxes + pad (cols 3198..3327) ----
#pragma unroll
  for (int it = 0; it < 3; ++it) {
    int idx = it * 64 + ln;
    if (idx < 130) {
      int c = 3198 + idx;
      float v = (idx < 82) ? fdec(umx[idx]) : 0.f;
      fA[COLADDR(c)] = __float2bfloat16(v);
    }
  }
#undef COLADDR
}

// ======================= tiled bf16 MFMA GEMM ==============================

__device__ __forceinline__ void gld_lds16(const void* gptr, void* l) {
  typedef const __attribute__((address_space(1))) unsigned int GU;
  typedef __attribute__((address_space(3))) unsigned int LU;
  __builtin_amdgcn_global_load_lds((GU*)gptr, (LU*)l, 16, 0, 0);
}

// gemm1: C tiled bf16 (next GEMM's A, outKT = Nn/64), +bias +relu; 128^2.
__global__ __launch_bounds__(256) void gemm_tiled(
    const short* __restrict__ A, const short* __restrict__ B,
    const float* __restrict__ bias, int Nreal,
    void* __restrict__ Cout, int Nn, int KT, int ktPerSplit, int outKT)
{
  __shared__ __align__(16) short lA[8192];
  __shared__ __align__(16) short lB[8192];
  const int tid = threadIdx.x;
  const int w = tid >> 6, L = tid & 63;
  const int lrow = L & 15, lch = L >> 4;
  const int mt = blockIdx.y, nt = blockIdx.x;
  const int mw = (w >> 1) * 4, nw = (w & 1) * 4;
  const int kt0 = blockIdx.z * ktPerSplit, kt1 = kt0 + ktPerSplit;

  const short* Ab = A + ((size_t)mt * KT) * 8192 + (size_t)L * 8;
  const short* Bb = B + ((size_t)nt * KT) * 8192 + (size_t)L * 8;

  f32x4 acc[4][4] = {};

  for (int kt = kt0; kt < kt1; ++kt) {
    const short* Ak = Ab + (size_t)kt * 8192;
    const short* Bk = Bb + (size_t)kt * 8192;
#pragma unroll
    for (int j = 0; j < 4; ++j) {
      int st = w * 4 + j;
      gld_lds16(Ak + st * 512, &lA[st * 512]);
      gld_lds16(Bk + st * 512, &lB[st * 512]);
    }
    __syncthreads();
#pragma unroll
    for (int kk = 0; kk < 2; ++kk) {
      bf16x8 af[4], bfr[4];
#pragma unroll
      for (int i = 0; i < 4; ++i) {
        af[i]  = *(const bf16x8*)&lA[((mw + i) * 2 + kk) * 512 + L * 8];
        bfr[i] = *(const bf16x8*)&lB[((nw + i) * 2 + kk) * 512 + L * 8];
      }
#pragma unroll
      for (int i = 0; i < 4; ++i)
#pragma unroll
        for (int j = 0; j < 4; ++j)
          acc[i][j] = __builtin_amdgcn_mfma_f32_16x16x32_bf16(af[i], bfr[j], acc[i][j], 0, 0, 0);
    }
    __syncthreads();
  }

  __hip_bfloat16* C = (__hip_bfloat16*)Cout;
#pragma unroll
  for (int j = 0; j < 4; ++j) {
    int n = nt * 128 + (nw + j) * 16 + lrow;
    float bn = (n < Nreal) ? bias[n] : 0.f;
    int kt = n >> 6, kq = (n >> 5) & 1, lc2 = (n >> 3) & 3, j2 = n & 7;
#pragma unroll
    for (int i = 0; i < 4; ++i) {
      int mi = mw + i;
      size_t base = ((((size_t)mt * outKT + kt) * 16) + mi * 2 + kq) * 512
                    + (size_t)(lch * 4) * 8 + (size_t)lc2 * 128 + j2;
#pragma unroll
      for (int r = 0; r < 4; ++r)
        C[base + r * 8] = __float2bfloat16(fmaxf(acc[i][j][r] + bn, 0.f));
    }
  }
}

// gemm2: 128^2, z=4, XCD-pinned B. Grid (1024,1,1):
//   nt = bid&7  -> XCD (= bid%8 round-robin) serves ONE B-panel (1.3MB,
//                  L2-resident for all 128 of its blocks)
//   mt = (bid>>3)&31, zz = bid>>8.
// fp16 partials P[4][4096][1024].
__global__ __launch_bounds__(256) void gemm2_128(
    const short* __restrict__ A, const short* __restrict__ B,
    __half* __restrict__ P)
{
  __shared__ __align__(16) short lA[8192];
  __shared__ __align__(16) short lB[8192];
  const int tid = threadIdx.x;
  const int w = tid >> 6, L = tid & 63;
  const int lrow = L & 15, lch = L >> 4;
  const int bid = blockIdx.x;
  const int nt = bid & 7, mt = (bid >> 3) & 31, zz = bid >> 8;
  const int mw = (w >> 1) * 4, nw = (w & 1) * 4;
  const int kt0 = zz * 20, kt1 = kt0 + 20;   // K=5120, KT=80, z=4

  const short* Ab = A + ((size_t)mt * 80) * 8192 + (size_t)L * 8;
  const short* Bb = B + ((size_t)nt * 80) * 8192 + (size_t)L * 8;

  f32x4 acc[4][4] = {};

  for (int kt = kt0; kt < kt1; ++kt) {
    const short* Ak = Ab + (size_t)kt * 8192;
    const short* Bk = Bb + (size_t)kt * 8192;
#pragma unroll
    for (int j = 0; j < 4; ++j) {
      int st = w * 4 + j;
      gld_lds16(Ak + st * 512, &lA[st * 512]);
      gld_lds16(Bk + st * 512, &lB[st * 512]);
    }
    __syncthreads();
#pragma unroll
    for (int kk = 0; kk < 2; ++kk) {
      bf16x8 af[4], bfr[4];
#pragma unroll
      for (int i = 0; i < 4; ++i) {
        af[i]  = *(const bf16x8*)&lA[((mw + i) * 2 + kk) * 512 + L * 8];
        bfr[i] = *(const bf16x8*)&lB[((nw + i) * 2 + kk) * 512 + L * 8];
      }
#pragma unroll
      for (int i = 0; i < 4; ++i)
#pragma unroll
        for (int j = 0; j < 4; ++j)
          acc[i][j] = __builtin_amdgcn_mfma_f32_16x16x32_bf16(af[i], bfr[j], acc[i][j], 0, 0, 0);
    }
    __syncthreads();
  }

  __half* Pz = P + (size_t)zz * 4096 * 1024;
#pragma unroll
  for (int j = 0; j < 4; ++j) {
    int n = nt * 128 + (nw + j) * 16 + lrow;
#pragma unroll
    for (int i = 0; i < 4; ++i)
#pragma unroll
      for (int r = 0; r < 4; ++r) {
        int m = mt * 128 + (mw + i) * 16 + lch * 4 + r;
        Pz[(size_t)m * 1024 + n] = __float2half(acc[i][j][r]);
      }
  }
}

// == final: relu(P0+P1+P2+P3+b2) @ W3 + b3 -> fp32 out (reduce fused) =======

__global__ __launch_bounds__(256) void gemm3_fused(
    const __half* __restrict__ P,     // [4][4096][1024] fp16
    const float* __restrict__ b2v,    // lb2 [1024]
    const float* __restrict__ W3,     // lW3 [1024,9]
    const float* __restrict__ b3v,    // lb3 [9]
    float* __restrict__ out)          // [4096,9]
{
  __shared__ float sW3[9 * 1024];
  int tid = threadIdx.x;
  for (int i = tid; i < 9216; i += 256) { int k = i / 9, j = i - 9 * k; sW3[j * 1024 + k] = W3[i]; }
  __syncthreads();
  int row = blockIdx.x * 4 + (tid >> 6);
  int lane = tid & 63;
  const __half* p0 = P + (size_t)row * 1024;
  const size_t S = (size_t)4096 * 1024;
  float acc[9] = {0, 0, 0, 0, 0, 0, 0, 0, 0};
  for (int t = 0; t < 16; ++t) {
    int k = lane + 64 * t;
    float c = __half2float(p0[k]) + __half2float(p0[k + S])
            + __half2float(p0[k + 2 * S]) + __half2float(p0[k + 3 * S]) + b2v[k];
    c = fmaxf(c, 0.f);
#pragma unroll
    for (int j = 0; j < 9; ++j) acc[j] += c * sW3[j * 1024 + k];
  }
#pragma unroll
  for (int j = 0; j < 9; ++j) {
    float v = acc[j];
    v += __shfl_down(v, 32, 64);
    v += __shfl_down(v, 16, 64);
    v += __shfl_down(v, 8, 64);
    v += __shfl_down(v, 4, 64);
    v += __shfl_down(v, 2, 64);
    v += __shfl_down(v, 1, 64);
    if (lane == 0) out[(size_t)row * 9 + j] = v + b3v[j];
  }
}

// ============================= launch =======================================

extern "C" void kernel_launch(void* const* d_in, const int* in_sizes, int n_in,
                              void* d_out, int out_size, void* d_ws, size_t ws_size,
                              hipStream_t stream)
{
  const float* x   = (const float*)d_in[0];
  const int*   ei  = (const int*)d_in[1];
  const float* W1  = (const float*)d_in[3];
  const float* a1s = (const float*)d_in[4];
  const float* a1d = (const float*)d_in[5];
  const float* b1  = (const float*)d_in[6];
  const float* W2  = (const float*)d_in[7];
  const float* a2s = (const float*)d_in[8];
  const float* a2d = (const float*)d_in[9];
  const float* b2  = (const float*)d_in[10];
  const float* W3  = (const float*)d_in[11];
  const float* a3s = (const float*)d_in[12];
  const float* a3d = (const float*)d_in[13];
  const float* b3  = (const float*)d_in[14];
  const float* lW1 = (const float*)d_in[15];
  const float* lb1 = (const float*)d_in[16];
  const float* lW2 = (const float*)d_in[17];
  const float* lb2 = (const float*)d_in[18];
  const float* lW3 = (const float*)d_in[19];
  const float* lb3 = (const float*)d_in[20];

  const int E = 4096 * 39 * 8;
  const int* esrc = ei;
  const int* edst = ei + E;

  // ws (bf16 elems): fA 13.6M | W1T 17.0M | C1 21.0M | W2T 5.2M  (~114 MB)
  short* fA  = (short*)d_ws;                       // tiled [4096,3328] KT=52
  short* W1T = fA  + (size_t)4096 * 3328;          // tiled [5120,3328] KT=52
  short* C1  = W1T + (size_t)5120 * 3328;          // tiled [4096,5120] KT=80
  short* W2T = C1  + (size_t)4096 * 5120;          // tiled [1024,5120] KT=80
  __half* P  = (__half*)d_ws;                      // 4x[4096,1024] fp16 (33.5MB), aliases fA+W1T (dead)

  gnn_conv_wpg<<<7488, 128, 0, stream>>>(x, esrc, edst,
                                         W1, a1s, a1d, b1, W2, a2s, a2d, b2, W3, a3s, a3d, b3,
                                         (__hip_bfloat16*)fA, lW1, lW2, W1T, W2T);
  gemm_tiled<<<dim3(40, 32, 1), 256, 0, stream>>>(fA, W1T, lb1, 5000, C1, 5120, 52, 52, 80);
  gemm2_128<<<dim3(1024, 1, 1), 256, 0, stream>>>(C1, W2T, P);
  gemm3_fused<<<1024, 256, 0, stream>>>(P, lb2, lW3, lb3, (float*)d_out);
}

// Round 13
// 426.073 us; speedup vs baseline: 1.0450x; 1.0034x over previous
//
#include <hip/hip_runtime.h>
#include <hip/hip_bf16.h>
#include <hip/hip_fp16.h>
#include <stdint.h>

// ---------------------------------------------------------------------------
// CCRGNN r26: gemm2 double-buffered with counted vmcnt across raw s_barrier
// (m218 pattern). Accounting: gemm2 does 80 iters/CU x 256cy MFMA = 8.5us of
// matrix work in ~130us (=6.5% util) because __syncthreads drains vmcnt(0)
// every iter, serially exposing the ~600-900cy L3/HBM A-stage. Fix: dbuf LDS
// (64KB, 2 blk/CU), per iter {STAGE(next buf); s_waitcnt vmcnt(8); s_barrier;
// compute(cur); s_barrier} -- prefetch stays in flight across the barrier.
// Each wave issues exactly 8 gld_lds/STAGE so vmcnt(8) = "my current tile
// landed" (FIFO, m135); barrier joins all waves -> tile visible. Mechanism is
// regime-matched: null on L2-hot gemm1-class (m99/m131) but pays in long-
// latency low-util regime (m218 +38-73%). Pinned-B (r25, +15us) kept.
// gnn (r24 wpg fp16-diet) / gemm1 / conv / gemm3 unchanged.
// ---------------------------------------------------------------------------

typedef float f32x4 __attribute__((ext_vector_type(4)));
typedef short bf16x8 __attribute__((ext_vector_type(8)));
typedef _Float16 f16x8 __attribute__((ext_vector_type(8)));

// monotone float<->uint encoding for atomicMax on floats
__device__ __forceinline__ unsigned fenc(float f) {
  int s = __float_as_int(f);
  return s < 0 ? ~(unsigned)s : ((unsigned)s | 0x80000000u);
}
__device__ __forceinline__ float fdec(unsigned u) {
  return (u & 0x80000000u) ? __int_as_float((int)(u & 0x7fffffffu))
                           : __int_as_float(~(int)u);
}

// wave-local LDS fence (gnn): drains this wave's LDS ops so other lanes'
// writes are visible. No s_barrier — waves never sync with each other.
__device__ __forceinline__ void wbar() {
  asm volatile("s_waitcnt lgkmcnt(0)" ::: "memory");
}

// ============ merged: wave-per-graph GNN + weight transpose ================
// bid < 2048 : gnn block = 2 independent graphs (g = bid*2 + wave)
// bid >= 2048: conv(tile = bid-2048)

__global__ __launch_bounds__(128) void gnn_conv_wpg(
    const float* __restrict__ x,
    const int* __restrict__ esrc, const int* __restrict__ edst,
    const float* __restrict__ W1, const float* __restrict__ a1s, const float* __restrict__ a1d, const float* __restrict__ b1,
    const float* __restrict__ W2, const float* __restrict__ a2s, const float* __restrict__ a2d, const float* __restrict__ b2,
    const float* __restrict__ W3, const float* __restrict__ a3s, const float* __restrict__ a3d, const float* __restrict__ b3,
    __hip_bfloat16* __restrict__ fA,         // tiled [4096,3328] KT=52
    const float* __restrict__ lW1, const float* __restrict__ lW2,
    short* __restrict__ W1T, short* __restrict__ W2T)
{
  __shared__ __align__(16) char smem[29024];
  const int tid = threadIdx.x;
  const int bid = blockIdx.x;

  if (bid >= 2048) {
    // ---- conv body (128 threads): fp32 [K0,N0] -> bf16 fragment-tiled ----
    float (*t)[260] = (float(*)[260])smem;
    const int cid = bid - 2048;
    const float* W; short* WT; int ktile, ntile, K0, N0, KT;
    if (cid < 4160) { W = lW1; WT = W1T; ktile = cid % 208; ntile = cid / 208; K0 = 3280; N0 = 5000; KT = 52; }
    else { int c2 = cid - 4160; W = lW2; WT = W2T; ktile = c2 % 320; ntile = c2 / 320; K0 = 5000; N0 = 1024; KT = 80; }

    const int kb = ktile * 16, nb = ntile * 256;
    const int wv = tid >> 6, lnc = tid & 63;
#pragma unroll
    for (int r = 0; r < 8; ++r) {
      int k = kb + wv * 8 + r;
      int n = nb + lnc * 4;
      f32x4 v = (f32x4){0.f, 0.f, 0.f, 0.f};
      if (k < K0 && n < N0) v = *(const f32x4*)&W[(size_t)k * N0 + n];   // N0 % 4 == 0
      *(f32x4*)&t[wv * 8 + r][lnc * 4] = v;
    }
    __syncthreads();
#pragma unroll
    for (int h = 0; h < 4; ++h) {
      int c = h * 128 + tid;
      int nl = c >> 1, kc = c & 1;
      int n = nb + nl, k = kb + kc * 8;
      union { bf16x8 v; __hip_bfloat16 b[8]; } z;
#pragma unroll
      for (int j = 0; j < 8; ++j) z.b[j] = __float2bfloat16(t[kc * 8 + j][nl]);
      int rt = n >> 7, mi = (n >> 4) & 7, lr = n & 15;
      int kt = k >> 6, kq = (k >> 5) & 1, lc = (k >> 3) & 3;
      size_t addr = ((((size_t)rt * KT) + kt) * 16 + mi * 2 + kq) * 512 + ((size_t)lr + 16 * lc) * 8;
      *(bf16x8*)&WT[addr] = z.v;
    }
    return;
  }

  // ---- gnn: wave-per-graph, barrier-free, fp16 A/HfT diet ----
  const int w = tid >> 6, ln = tid & 63;
  const int g = bid * 2 + w;

  // block-shared (read-only weights)
  float* sW3T  = (float*)(smem);                 // W3^T [9][68]
  float* a2buf = (float*)(smem + 2448);          // a2s | a2d
  float* a3sb  = (float*)(smem + 2960);
  float* a3db  = (float*)(smem + 3008);
  float* b3b   = (float*)(smem + 3056);
  // per-graph slice (one per wave), 12960 B
  char* sl = smem + 3104 + w * 12960;
  __half*   Ah   = (__half*)  (sl);              // [39][48] fp16 (scaled 2^-8)
  __half*   Hh2  = (__half*)  (sl + 3744);       // [39][72] half
  __half*   h1h  = (__half*)  (sl + 9360);       // [312] half
  __half*   HfT16= (__half*)  (sl + 9984);       // [9][48] fp16
  float*    xbuf = (float*)   (sl + 10848);      // 40 f
  float*    sarr = (float*)   (sl + 11008);      // 40 f
  float*    darr = (float*)   (sl + 11168);      // 40 f
  float*    den  = (float*)   (sl + 11328);      // 40 f (1/scaled-den)
  unsigned* umx  = (unsigned*)(sl + 11488);      // 132 u32
  unsigned* cntP = (unsigned*)(sl + 12016);      // 234 u32 (4-bit cnt[39][<=48])

  const int rt = g >> 7, mi = (g >> 4) & 7, lrow = g & 15;
  const size_t gbase = (size_t)rt * 52 * 8192 + (size_t)(mi * 2) * 512 + (size_t)lrow * 8;
#define COLADDR(c) (gbase + (size_t)((c) >> 6) * 8192 + (size_t)(((c) >> 5) & 1) * 512 \
                    + (size_t)(((c) >> 3) & 3) * 128 + ((c) & 7))

  // ---- setup ----
  for (int i = tid; i < 576; i += 128) { int k = i / 9, f3 = i - 9 * k; sW3T[f3 * 68 + k] = W3[i]; }
  a2buf[tid] = (tid < 64) ? a2s[tid] : a2d[tid - 64];
  if (tid < 9) { a3sb[tid] = a3s[tid]; a3db[tid] = a3d[tid]; b3b[tid] = b3[tid]; }
  for (int i = ln; i < 132; i += 64) umx[i] = 0u;
  for (int i = ln; i < 234; i += 64) cntP[i] = 0u;
  if (ln < 40) xbuf[ln] = 0.f;
  if (ln == 39) { sarr[39] = 0.f; darr[39] = 0.f; }
  __syncthreads();   // the ONLY block barrier (shared weights ready)

  float xv = 0.f;
  if (ln < 39) { xv = x[g * 39 + ln]; xbuf[ln] = xv; fA[COLADDR(ln)] = __float2bfloat16(xv); }
  float c_s = 0.f, c_d = 0.f;
  const float w1r = W1[ln & 7], b1r = b1[ln & 7];
#pragma unroll
  for (int ff = 0; ff < 8; ++ff) { float wv = W1[ff]; c_s += wv * a1s[ff]; c_d += wv * a1d[ff]; }
  const int eb = g * 312, nb0 = g * 39;
  if (ln < 39) atomicMax(&umx[0], fenc(xv));
#pragma unroll
  for (int it = 0; it < 6; ++it) {                     // cnt build (one pass)
    int e = it * 64 + ln;
    if (e < 351) {
      int ls, ld;
      if (e < 312) { ls = esrc[eb + e] - nb0; ld = edst[eb + e] - nb0; }
      else         { ls = e - 312; ld = ls; }
      atomicAdd(&cntP[ld * 6 + (ls >> 3)], 1u << (4 * (ls & 7)));
    }
  }
  wbar();

  // fused dense softmax -> Ah (fp16, scaled 2^-8) + 1/den (scaled).
  // Scale cancels exactly in num/den; den sums the ROUNDED stored weights.
  auto denseEW = [&](const float* sv, const float* dv) {
    if (ln < 39) {
      unsigned cw[6];
#pragma unroll
      for (int j = 0; j < 6; ++j) cw[j] = cntP[ln * 6 + j];
      float dval = dv[ln];
      __half* Ar = &Ah[ln * 48];
      float sum = 0.f;
#pragma unroll
      for (int c = 0; c < 5; ++c) {
        union { f16x8 v; __half h[8]; } z8;
#pragma unroll
        for (int j = 0; j < 8; ++j) {
          int s = c * 8 + j;
          float e = sv[s] + dval;
          e = (e > 0.f) ? e : 0.2f * e;
          unsigned cc = (cw[s >> 3] >> (4 * (s & 7))) & 0xFu;
          float ex = __expf(e) * 0.00390625f;        // 2^-8 fp16 headroom
          float wv = cc ? (float)cc * ex : 0.f;
          z8.h[j] = __float2half(wv);
          sum += (float)z8.h[j];                     // sum the rounded value
        }
        *(f16x8*)&Ar[c * 8] = z8.v;
      }
      den[ln] = 1.f / (sum + 3.9e-19f);              // 1e-16 * 2^-8
    }
  };

  // ========== layer 1 (Fin=1): softmax+q fused, no A storage ==========
  if (ln < 39) {
    unsigned cw[6];
#pragma unroll
    for (int j = 0; j < 6; ++j) cw[j] = cntP[ln * 6 + j];
    float dval = xbuf[ln] * c_d;
    float q = 0.f, dsum = 0.f;
#pragma unroll
    for (int c = 0; c < 10; ++c) {
      f32x4 x4 = *(const f32x4*)&xbuf[c * 4];
#pragma unroll
      for (int j = 0; j < 4; ++j) {
        int s = c * 4 + j;
        float xs = x4[j];
        float e = xs * c_s + dval;
        e = (e > 0.f) ? e : 0.2f * e;
        unsigned cc = (cw[s >> 3] >> (4 * (s & 7))) & 0xFu;
        float ex = __expf(e);
        float wv = cc ? (float)cc * ex : 0.f;
        q += wv * xs; dsum += wv;
      }
    }
    sarr[ln] = q * (1.f / (dsum + 1e-16f));
  }
  wbar();
#pragma unroll
  for (int it = 0; it < 5; ++it) {                     // h1 = relu(q W1 + b1)
    int slot = it * 64 + ln;                           // slot&7 == ln&7
    if (slot < 312) {
      int i = slot >> 3;
      float v = fmaxf(sarr[i] * w1r + b1r, 0.f);
      h1h[slot] = __float2half(v);
      fA[COLADDR(39 + slot)] = __float2bfloat16(v);
      atomicMax(&umx[1 + (ln & 7)], fenc(v));
    }
  }
  wbar();

  // ========== layer 2 (Fin=8, Fout=64) ==========
  float ht2r[40];                                      // Ht2 column f=ln
  {
    float w2k[8];
#pragma unroll
    for (int k = 0; k < 8; ++k) w2k[k] = W2[k * 64 + ln];
#pragma unroll
    for (int i = 0; i < 39; ++i) {
      f16x8 hr = *(const f16x8*)&h1h[i * 8];
      float hv = 0.f;
#pragma unroll
      for (int k = 0; k < 8; ++k) hv += (float)hr[k] * w2k[k];
      ht2r[i] = hv;
    }
    ht2r[39] = 0.f;
#pragma unroll
    for (int i = 0; i < 39; ++i) Hh2[i * 72 + ln] = __float2half(ht2r[i]);
  }
  wbar();
#pragma unroll
  for (int rr = 0; rr < 2; ++rr) {                     // s-dots then d-dots
    int t = rr * 64 + ln;
    if (t < 78) {
      int node = (t < 39) ? t : t - 39;
      const float* ab = a2buf + ((t < 39) ? 0 : 64);
      const __half* hr = &Hh2[node * 72];
      float s = 0.f;
#pragma unroll
      for (int c = 0; c < 8; ++c) {
        f16x8 hv = *(const f16x8*)&hr[c * 8];
        f32x4 a0 = *(const f32x4*)&ab[c * 8];
        f32x4 a1 = *(const f32x4*)&ab[c * 8 + 4];
        s += (float)hv[0] * a0.x + (float)hv[1] * a0.y + (float)hv[2] * a0.z + (float)hv[3] * a0.w
           + (float)hv[4] * a1.x + (float)hv[5] * a1.y + (float)hv[6] * a1.z + (float)hv[7] * a1.w;
      }
      if (t < 39) sarr[node] = s; else darr[node] = s;
    }
  }
  wbar();
  denseEW(sarr, darr);
  wbar();
  {                                                    // h2 = relu(Ah ht2r * invden + b2)
    const float b2r = b2[ln];
    for (int i = 0; i < 39; ++i) {
      float inv = den[i];
      const __half* Ar = &Ah[i * 48];
      float acc = 0.f;
#pragma unroll
      for (int c = 0; c < 5; ++c) {
        f16x8 a8 = *(const f16x8*)&Ar[c * 8];
#pragma unroll
        for (int j = 0; j < 8; ++j) acc += (float)a8[j] * ht2r[c * 8 + j];
      }
      float v = fmaxf(acc * inv + b2r, 0.f);
      Hh2[i * 72 + ln] = __float2half(v);
      fA[COLADDR(351 + i * 64 + ln)] = __float2bfloat16(v);
      atomicMax(&umx[9 + ln], fenc(v));
    }
  }
  wbar();

  // ========== layer 3 (Fin=64, Fout=9) ==========
#pragma unroll
  for (int it = 0; it < 6; ++it) {                     // Ht3^T = (h2 @ W3)^T, fp16
    int slot = it * 64 + ln;
    if (slot < 351) {
      int i = slot / 9, f3 = slot - 9 * i;
      const __half* hr = &Hh2[i * 72];
      const float* wr = &sW3T[f3 * 68];
      float acc = 0.f;
#pragma unroll
      for (int c = 0; c < 8; ++c) {
        f16x8 hv = *(const f16x8*)&hr[c * 8];
        f32x4 w0 = *(const f32x4*)&wr[c * 8];
        f32x4 w1 = *(const f32x4*)&wr[c * 8 + 4];
        acc += (float)hv[0] * w0.x + (float)hv[1] * w0.y + (float)hv[2] * w0.z + (float)hv[3] * w0.w
             + (float)hv[4] * w1.x + (float)hv[5] * w1.y + (float)hv[6] * w1.z + (float)hv[7] * w1.w;
      }
      HfT16[f3 * 48 + i] = __float2half(acc);
    }
  }
  if (ln < 9) HfT16[ln * 48 + 39] = __float2half(0.f);
  wbar();
#pragma unroll
  for (int rr = 0; rr < 2; ++rr) {
    int t = rr * 64 + ln;
    if (t < 78) {
      int node = (t < 39) ? t : t - 39;
      const float* av = (t < 39) ? a3sb : a3db;
      float s = 0.f;
#pragma unroll
      for (int f3 = 0; f3 < 9; ++f3) s += (float)HfT16[f3 * 48 + node] * av[f3];
      if (t < 39) sarr[node] = s; else darr[node] = s;
    }
  }
  wbar();
  denseEW(sarr, darr);
  wbar();
#pragma unroll
  for (int it = 0; it < 6; ++it) {                     // h3 = relu(Ah Ht3 * invden + b3)
    int slot = it * 64 + ln;
    if (slot < 351) {
      int i = slot / 9, f3 = slot - 9 * i;
      float inv = den[i];
      const __half* Ar = &Ah[i * 48];
      const __half* Hr = &HfT16[f3 * 48];
      float acc = 0.f;
#pragma unroll
      for (int c = 0; c < 5; ++c) {
        f16x8 a8 = *(const f16x8*)&Ar[c * 8];
        f16x8 h8 = *(const f16x8*)&Hr[c * 8];
#pragma unroll
        for (int j = 0; j < 8; ++j) acc += (float)a8[j] * (float)h8[j];
      }
      float v = fmaxf(acc * inv + b3b[f3], 0.f);
      fA[COLADDR(2847 + slot)] = __float2bfloat16(v);
      atomicMax(&umx[73 + f3], fenc(v));
    }
  }
  wbar();

  // ---- segment maxes + pad (cols 3198..3327) ----
#pragma unroll
  for (int it = 0; it < 3; ++it) {
    int idx = it * 64 + ln;
    if (idx < 130) {
      int c = 3198 + idx;
      float v = (idx < 82) ? fdec(umx[idx]) : 0.f;
      fA[COLADDR(c)] = __float2bfloat16(v);
    }
  }
#undef COLADDR
}

// ======================= tiled bf16 MFMA GEMM ==============================

__device__ __forceinline__ void gld_lds16(const void* gptr, void* l) {
  typedef const __attribute__((address_space(1))) unsigned int GU;
  typedef __attribute__((address_space(3))) unsigned int LU;
  __builtin_amdgcn_global_load_lds((GU*)gptr, (LU*)l, 16, 0, 0);
}

// gemm1: C tiled bf16 (next GEMM's A, outKT = Nn/64), +bias +relu; 128^2.
__global__ __launch_bounds__(256) void gemm_tiled(
    const short* __restrict__ A, const short* __restrict__ B,
    const float* __restrict__ bias, int Nreal,
    void* __restrict__ Cout, int Nn, int KT, int ktPerSplit, int outKT)
{
  __shared__ __align__(16) short lA[8192];
  __shared__ __align__(16) short lB[8192];
  const int tid = threadIdx.x;
  const int w = tid >> 6, L = tid & 63;
  const int lrow = L & 15, lch = L >> 4;
  const int mt = blockIdx.y, nt = blockIdx.x;
  const int mw = (w >> 1) * 4, nw = (w & 1) * 4;
  const int kt0 = blockIdx.z * ktPerSplit, kt1 = kt0 + ktPerSplit;

  const short* Ab = A + ((size_t)mt * KT) * 8192 + (size_t)L * 8;
  const short* Bb = B + ((size_t)nt * KT) * 8192 + (size_t)L * 8;

  f32x4 acc[4][4] = {};

  for (int kt = kt0; kt < kt1; ++kt) {
    const short* Ak = Ab + (size_t)kt * 8192;
    const short* Bk = Bb + (size_t)kt * 8192;
#pragma unroll
    for (int j = 0; j < 4; ++j) {
      int st = w * 4 + j;
      gld_lds16(Ak + st * 512, &lA[st * 512]);
      gld_lds16(Bk + st * 512, &lB[st * 512]);
    }
    __syncthreads();
#pragma unroll
    for (int kk = 0; kk < 2; ++kk) {
      bf16x8 af[4], bfr[4];
#pragma unroll
      for (int i = 0; i < 4; ++i) {
        af[i]  = *(const bf16x8*)&lA[((mw + i) * 2 + kk) * 512 + L * 8];
        bfr[i] = *(const bf16x8*)&lB[((nw + i) * 2 + kk) * 512 + L * 8];
      }
#pragma unroll
      for (int i = 0; i < 4; ++i)
#pragma unroll
        for (int j = 0; j < 4; ++j)
          acc[i][j] = __builtin_amdgcn_mfma_f32_16x16x32_bf16(af[i], bfr[j], acc[i][j], 0, 0, 0);
    }
    __syncthreads();
  }

  __hip_bfloat16* C = (__hip_bfloat16*)Cout;
#pragma unroll
  for (int j = 0; j < 4; ++j) {
    int n = nt * 128 + (nw + j) * 16 + lrow;
    float bn = (n < Nreal) ? bias[n] : 0.f;
    int kt = n >> 6, kq = (n >> 5) & 1, lc2 = (n >> 3) & 3, j2 = n & 7;
#pragma unroll
    for (int i = 0; i < 4; ++i) {
      int mi = mw + i;
      size_t base = ((((size_t)mt * outKT + kt) * 16) + mi * 2 + kq) * 512
                    + (size_t)(lch * 4) * 8 + (size_t)lc2 * 128 + j2;
#pragma unroll
      for (int r = 0; r < 4; ++r)
        C[base + r * 8] = __float2bfloat16(fmaxf(acc[i][j][r] + bn, 0.f));
    }
  }
}

// gemm2: 128^2, z=4, XCD-pinned B (r25) + double-buffered LDS with counted
// vmcnt across raw s_barrier (m218 pattern). Grid (1024,1,1):
//   nt = bid&7 (XCD-pinned B-panel), mt = (bid>>3)&31, zz = bid>>8.
// Per iter: STAGE(next, buf^1) -> s_waitcnt vmcnt(8) (my 8 current-tile
// loads landed; 8 prefetch stay in flight) -> s_barrier -> MFMA(cur) ->
// s_barrier (buffer-reuse guard). fp16 partials P[4][4096][1024].
__global__ __launch_bounds__(256) void gemm2_128(
    const short* __restrict__ A, const short* __restrict__ B,
    __half* __restrict__ P)
{
  __shared__ __align__(16) short lA[2][8192];
  __shared__ __align__(16) short lB[2][8192];
  const int tid = threadIdx.x;
  const int w = tid >> 6, L = tid & 63;
  const int lrow = L & 15, lch = L >> 4;
  const int bid = blockIdx.x;
  const int nt = bid & 7, mt = (bid >> 3) & 31, zz = bid >> 8;
  const int mw = (w >> 1) * 4, nw = (w & 1) * 4;
  const int kt0 = zz * 20, kt1 = kt0 + 20;   // K=5120, KT=80, z=4

  const short* Ab = A + ((size_t)mt * 80) * 8192 + (size_t)L * 8;
  const short* Bb = B + ((size_t)nt * 80) * 8192 + (size_t)L * 8;

  f32x4 acc[4][4] = {};

  // stage tile kt into buffer b: exactly 8 gld_lds per wave
  auto STAGE = [&](int b, int kt) {
    const short* Ak = Ab + (size_t)kt * 8192;
    const short* Bk = Bb + (size_t)kt * 8192;
#pragma unroll
    for (int j = 0; j < 4; ++j) {
      int st = w * 4 + j;
      gld_lds16(Ak + st * 512, &lA[b][st * 512]);
      gld_lds16(Bk + st * 512, &lB[b][st * 512]);
    }
  };

  STAGE(0, kt0);
  for (int kt = kt0; kt < kt1; ++kt) {
    const int cur = (kt - kt0) & 1;
    if (kt + 1 < kt1) {
      STAGE(cur ^ 1, kt + 1);
      asm volatile("s_waitcnt vmcnt(8)" ::: "memory");   // cur tile landed
    } else {
      asm volatile("s_waitcnt vmcnt(0)" ::: "memory");
    }
    asm volatile("s_barrier" ::: "memory");              // all waves' cur visible
#pragma unroll
    for (int kk = 0; kk < 2; ++kk) {
      bf16x8 af[4], bfr[4];
#pragma unroll
      for (int i = 0; i < 4; ++i) {
        af[i]  = *(const bf16x8*)&lA[cur][((mw + i) * 2 + kk) * 512 + L * 8];
        bfr[i] = *(const bf16x8*)&lB[cur][((nw + i) * 2 + kk) * 512 + L * 8];
      }
#pragma unroll
      for (int i = 0; i < 4; ++i)
#pragma unroll
        for (int j = 0; j < 4; ++j)
          acc[i][j] = __builtin_amdgcn_mfma_f32_16x16x32_bf16(af[i], bfr[j], acc[i][j], 0, 0, 0);
    }
    asm volatile("s_barrier" ::: "memory");              // buffer-reuse guard
  }

  __half* Pz = P + (size_t)zz * 4096 * 1024;
#pragma unroll
  for (int j = 0; j < 4; ++j) {
    int n = nt * 128 + (nw + j) * 16 + lrow;
#pragma unroll
    for (int i = 0; i < 4; ++i)
#pragma unroll
      for (int r = 0; r < 4; ++r) {
        int m = mt * 128 + (mw + i) * 16 + lch * 4 + r;
        Pz[(size_t)m * 1024 + n] = __float2half(acc[i][j][r]);
      }
  }
}

// == final: relu(P0+P1+P2+P3+b2) @ W3 + b3 -> fp32 out (reduce fused) =======

__global__ __launch_bounds__(256) void gemm3_fused(
    const __half* __restrict__ P,     // [4][4096][1024] fp16
    const float* __restrict__ b2v,    // lb2 [1024]
    const float* __restrict__ W3,     // lW3 [1024,9]
    const float* __restrict__ b3v,    // lb3 [9]
    float* __restrict__ out)          // [4096,9]
{
  __shared__ float sW3[9 * 1024];
  int tid = threadIdx.x;
  for (int i = tid; i < 9216; i += 256) { int k = i / 9, j = i - 9 * k; sW3[j * 1024 + k] = W3[i]; }
  __syncthreads();
  int row = blockIdx.x * 4 + (tid >> 6);
  int lane = tid & 63;
  const __half* p0 = P + (size_t)row * 1024;
  const size_t S = (size_t)4096 * 1024;
  float acc[9] = {0, 0, 0, 0, 0, 0, 0, 0, 0};
  for (int t = 0; t < 16; ++t) {
    int k = lane + 64 * t;
    float c = __half2float(p0[k]) + __half2float(p0[k + S])
            + __half2float(p0[k + 2 * S]) + __half2float(p0[k + 3 * S]) + b2v[k];
    c = fmaxf(c, 0.f);
#pragma unroll
    for (int j = 0; j < 9; ++j) acc[j] += c * sW3[j * 1024 + k];
  }
#pragma unroll
  for (int j = 0; j < 9; ++j) {
    float v = acc[j];
    v += __shfl_down(v, 32, 64);
    v += __shfl_down(v, 16, 64);
    v += __shfl_down(v, 8, 64);
    v += __shfl_down(v, 4, 64);
    v += __shfl_down(v, 2, 64);
    v += __shfl_down(v, 1, 64);
    if (lane == 0) out[(size_t)row * 9 + j] = v + b3v[j];
  }
}

// ============================= launch =======================================

extern "C" void kernel_launch(void* const* d_in, const int* in_sizes, int n_in,
                              void* d_out, int out_size, void* d_ws, size_t ws_size,
                              hipStream_t stream)
{
  const float* x   = (const float*)d_in[0];
  const int*   ei  = (const int*)d_in[1];
  const float* W1  = (const float*)d_in[3];
  const float* a1s = (const float*)d_in[4];
  const float* a1d = (const float*)d_in[5];
  const float* b1  = (const float*)d_in[6];
  const float* W2  = (const float*)d_in[7];
  const float* a2s = (const float*)d_in[8];
  const float* a2d = (const float*)d_in[9];
  const float* b2  = (const float*)d_in[10];
  const float* W3  = (const float*)d_in[11];
  const float* a3s = (const float*)d_in[12];
  const float* a3d = (const float*)d_in[13];
  const float* b3  = (const float*)d_in[14];
  const float* lW1 = (const float*)d_in[15];
  const float* lb1 = (const float*)d_in[16];
  const float* lW2 = (const float*)d_in[17];
  const float* lb2 = (const float*)d_in[18];
  const float* lW3 = (const float*)d_in[19];
  const float* lb3 = (const float*)d_in[20];

  const int E = 4096 * 39 * 8;
  const int* esrc = ei;
  const int* edst = ei + E;

  // ws (bf16 elems): fA 13.6M | W1T 17.0M | C1 21.0M | W2T 5.2M  (~114 MB)
  short* fA  = (short*)d_ws;                       // tiled [4096,3328] KT=52
  short* W1T = fA  + (size_t)4096 * 3328;          // tiled [5120,3328] KT=52
  short* C1  = W1T + (size_t)5120 * 3328;          // tiled [4096,5120] KT=80
  short* W2T = C1  + (size_t)4096 * 5120;          // tiled [1024,5120] KT=80
  __half* P  = (__half*)d_ws;                      // 4x[4096,1024] fp16 (33.5MB), aliases fA+W1T (dead)

  gnn_conv_wpg<<<7488, 128, 0, stream>>>(x, esrc, edst,
                                         W1, a1s, a1d, b1, W2, a2s, a2d, b2, W3, a3s, a3d, b3,
                                         (__hip_bfloat16*)fA, lW1, lW2, W1T, W2T);
  gemm_tiled<<<dim3(40, 32, 1), 256, 0, stream>>>(fA, W1T, lb1, 5000, C1, 5120, 52, 52, 80);
  gemm2_128<<<dim3(1024, 1, 1), 256, 0, stream>>>(C1, W2T, P);
  gemm3_fused<<<1024, 256, 0, stream>>>(P, lb2, lW3, lb3, (float*)d_out);
}